// Round 5
// baseline (442.298 us; speedup 1.0000x reference)
//
#include <hip/hip_runtime.h>
#include <hip/hip_bf16.h>

#define CC 16
#define BB 16384
#define DD 256
#define BT 16
#define NT 512
#define SLAB ((size_t)BB * DD)

typedef float f32x4 __attribute__((ext_vector_type(4)));
typedef short bf16x8 __attribute__((ext_vector_type(8)));
typedef short bf16x4 __attribute__((ext_vector_type(4)));

static __device__ __forceinline__ short bfc(float f) {
    return (short)__builtin_bit_cast(unsigned short, __float2bfloat16(f));
}
static __device__ __forceinline__ bf16x8 pack8(f32x4 a, f32x4 b) {
    bf16x8 v;
    v[0] = bfc(a[0]); v[1] = bfc(a[1]); v[2] = bfc(a[2]); v[3] = bfc(a[3]);
    v[4] = bfc(b[0]); v[5] = bfc(b[1]); v[6] = bfc(b[2]); v[7] = bfc(b[3]);
    return v;
}
static __device__ __forceinline__ float sigm(float x) {
    return __builtin_amdgcn_rcpf(1.0f + __expf(-x));
}
static __device__ __forceinline__ float tanh_(float x) {
    return 2.0f * __builtin_amdgcn_rcpf(1.0f + __expf(-2.0f * x)) - 1.0f;
}

// ---- prep: pack Wf (rows 0..255) + Wiou (rows 256..1023) f32 -> bf16 row-major
__global__ void prep(const float* __restrict__ Wf, const float* __restrict__ Wiou,
                     short* __restrict__ ws) {
    const int row = blockIdx.x;          // 0..1023
    const int t   = threadIdx.x;         // 0..63
    const float* src = (row < 256) ? (Wf + (size_t)row * DD)
                                   : (Wiou + (size_t)(row - 256) * DD);
    f32x4 v = *(const f32x4*)(src + t * 4);
    bf16x4 o; o[0] = bfc(v[0]); o[1] = bfc(v[1]); o[2] = bfc(v[2]); o[3] = bfc(v[3]);
    *(bf16x4*)(ws + (size_t)row * DD + t * 4) = o;
}

// ---- main: TreeLSTM node update, pair-staged pipeline.
// 512 thr = 8 waves; BT=16 rows x 256 cols; wave owns 32 cols.
// LDS: 2 pair-buffers x 2 children x 8KB bf16 tiles, 4-bit XOR swizzle
// (chunk ^ row) -> conflict-free b128 read+write. ONE barrier per 2 children
// (lgkmcnt-only drain; global loads cross it). h-pair issued at phase top,
// written at phase end; cm 1 child ahead; odd-child nmv after the barrier.
__global__ __launch_bounds__(NT, 4) void treelstm(
    const float* __restrict__ cmem,   // [C][B][D]
    const float* __restrict__ chid,   // [C][B][D]
    const short* __restrict__ wpk,    // packed bf16: Wf rows 0..255, Wiou 256..1023
    const float* __restrict__ bfv,    // [D]
    const float* __restrict__ biou,   // [3D]
    float* __restrict__ out)          // [2][B][D]
{
    __shared__ __align__(64) unsigned char hb[2][2][BT * DD * 2];   // 32 KiB

    const int tid  = threadIdx.x;
    const int lane = tid & 63;
    const int wid  = tid >> 6;     // 0..7
    const int l15  = lane & 15;
    const int l4   = lane >> 4;    // 0..3
    const int b0   = blockIdx.x * BT;
    const int wc0  = wid * 32;     // wave's 32 output columns
    const int swr  = l15 << 4;     // read-side 4-bit XOR (x16B)

    // staging: thread owns (row tid>>5, 16B-chunk tid&31)
    const int srow   = tid >> 5;
    const int schunk = tid & 31;
    const float* hg  = chid + (size_t)(b0 + srow) * DD + schunk * 8;
    const int wb     = srow * 512 + (((schunk ^ srow) & 31) << 4);

    // ---- issue h(0),h(1) first (weight setup hides latency)
    f32x4 hA0 = *(const f32x4*)(hg);
    f32x4 hA1 = *(const f32x4*)(hg + 4);
    f32x4 hA2 = *(const f32x4*)(hg + SLAB);
    f32x4 hA3 = *(const f32x4*)(hg + SLAB + 4);

    // Wf B-frags from packed bf16: 2 n-frags x 8 k = 32 VGPR
    bf16x8 wfr[2][8];
    float bfr[2];
#pragma unroll
    for (int n = 0; n < 2; ++n) {
        const short* wr = wpk + (size_t)(wc0 + n * 16 + l15) * DD + l4 * 8;
#pragma unroll
        for (int k = 0; k < 8; ++k) wfr[n][k] = *(const bf16x8*)(wr + k * 32);
        bfr[n] = bfv[wc0 + n * 16 + l15];
    }

    // cm base (C-frag layout: rows l4*4+j, col wc0+n*16+l15); cmE = cm(0)
    const float* cmp = cmem + (size_t)(b0 + l4 * 4) * DD + wc0 + l15;
    float cmE[8], cmO[8];
#pragma unroll
    for (int n = 0; n < 2; ++n)
#pragma unroll
        for (int j = 0; j < 4; ++j) cmE[n * 4 + j] = cmp[j * DD + n * 16];

    float hs[8], nmv[8];
#pragma unroll
    for (int i = 0; i < 8; ++i) { hs[i] = 0.f; nmv[i] = 0.f; }

    // ---- prologue: hs += pair0; write pair0 -> buffer 0; barrier
#pragma unroll
    for (int i = 0; i < 4; ++i) {
        hs[i] += hA0[i] + hA2[i];
        hs[4 + i] += hA1[i] + hA3[i];
    }
    *(bf16x8*)(&hb[0][0][0] + wb) = pack8(hA0, hA1);
    *(bf16x8*)(&hb[0][1][0] + wb) = pack8(hA2, hA3);
    asm volatile("s_waitcnt lgkmcnt(0)" ::: "memory");
    __builtin_amdgcn_s_barrier();
    __builtin_amdgcn_sched_barrier(0);

    const float* hgn = hg + 2 * SLAB;   // next-pair h source (children 2,3)
    const float* cmn = cmp + SLAB;      // next cm source (child 1)

#pragma unroll 1
    for (int P = 0; P < 8; ++P) {       // pair P = children {2P, 2P+1}
        // issue next pair's h (written to LDS at phase end)
        if (P < 7) {
            hA0 = *(const f32x4*)(hgn);
            hA1 = *(const f32x4*)(hgn + 4);
            hA2 = *(const f32x4*)(hgn + SLAB);
            hA3 = *(const f32x4*)(hgn + SLAB + 4);
            hgn += 2 * SLAB;
        }
        // issue cmO = cm(2P+1)
#pragma unroll
        for (int n = 0; n < 2; ++n)
#pragma unroll
            for (int j = 0; j < 4; ++j) cmO[n * 4 + j] = cmn[j * DD + n * 16];
        cmn += SLAB;

        // ---- child even: 8 ds_read_b128 + 16 MFMA (split accs, depth 4)
        f32x4 e0 = {bfr[0], bfr[0], bfr[0], bfr[0]};
        f32x4 e1 = {bfr[1], bfr[1], bfr[1], bfr[1]};
        f32x4 e2 = {0.f, 0.f, 0.f, 0.f}, e3 = {0.f, 0.f, 0.f, 0.f};
        const unsigned char* bcE = &hb[P & 1][0][0] + l15 * 512;
#pragma unroll
        for (int kk = 0; kk < 4; ++kk) {
            bf16x8 a = *(const bf16x8*)(bcE + ((((kk) << 6) + (l4 << 4)) ^ swr));
            e0 = __builtin_amdgcn_mfma_f32_16x16x32_bf16(a, wfr[0][kk], e0, 0, 0, 0);
            e1 = __builtin_amdgcn_mfma_f32_16x16x32_bf16(a, wfr[1][kk], e1, 0, 0, 0);
        }
#pragma unroll
        for (int kk = 4; kk < 8; ++kk) {
            bf16x8 a = *(const bf16x8*)(bcE + ((((kk) << 6) + (l4 << 4)) ^ swr));
            e2 = __builtin_amdgcn_mfma_f32_16x16x32_bf16(a, wfr[0][kk], e2, 0, 0, 0);
            e3 = __builtin_amdgcn_mfma_f32_16x16x32_bf16(a, wfr[1][kk], e3, 0, 0, 0);
        }
        // even nmv (fills odd child's ds_read shadow)
#pragma unroll
        for (int j = 0; j < 4; ++j) {
            nmv[j]     += sigm(e0[j] + e2[j]) * cmE[j];
            nmv[4 + j] += sigm(e1[j] + e3[j]) * cmE[4 + j];
        }
        // refill cmE = cm(2P+2)
        if (P < 7) {
#pragma unroll
            for (int n = 0; n < 2; ++n)
#pragma unroll
                for (int j = 0; j < 4; ++j) cmE[n * 4 + j] = cmn[j * DD + n * 16];
        }
        cmn += SLAB;

        // ---- child odd
        f32x4 o0 = {bfr[0], bfr[0], bfr[0], bfr[0]};
        f32x4 o1 = {bfr[1], bfr[1], bfr[1], bfr[1]};
        f32x4 o2 = {0.f, 0.f, 0.f, 0.f}, o3 = {0.f, 0.f, 0.f, 0.f};
        const unsigned char* bcO = &hb[P & 1][1][0] + l15 * 512;
#pragma unroll
        for (int kk = 0; kk < 4; ++kk) {
            bf16x8 a = *(const bf16x8*)(bcO + ((((kk) << 6) + (l4 << 4)) ^ swr));
            o0 = __builtin_amdgcn_mfma_f32_16x16x32_bf16(a, wfr[0][kk], o0, 0, 0, 0);
            o1 = __builtin_amdgcn_mfma_f32_16x16x32_bf16(a, wfr[1][kk], o1, 0, 0, 0);
        }
#pragma unroll
        for (int kk = 4; kk < 8; ++kk) {
            bf16x8 a = *(const bf16x8*)(bcO + ((((kk) << 6) + (l4 << 4)) ^ swr));
            o2 = __builtin_amdgcn_mfma_f32_16x16x32_bf16(a, wfr[0][kk], o2, 0, 0, 0);
            o3 = __builtin_amdgcn_mfma_f32_16x16x32_bf16(a, wfr[1][kk], o3, 0, 0, 0);
        }

        // ---- hs += next pair; write it; ONE barrier per pair
        if (P < 7) {
#pragma unroll
            for (int i = 0; i < 4; ++i) {
                hs[i] += hA0[i] + hA2[i];
                hs[4 + i] += hA1[i] + hA3[i];
            }
            *(bf16x8*)(&hb[(P & 1) ^ 1][0][0] + wb) = pack8(hA0, hA1);
            *(bf16x8*)(&hb[(P & 1) ^ 1][1][0] + wb) = pack8(hA2, hA3);
            asm volatile("s_waitcnt lgkmcnt(0)" ::: "memory");
            __builtin_amdgcn_s_barrier();
            __builtin_amdgcn_sched_barrier(0);
        }

        // odd nmv (post-barrier: fills next phase's ds_read window)
#pragma unroll
        for (int j = 0; j < 4; ++j) {
            nmv[j]     += sigm(o0[j] + o2[j]) * cmO[j];
            nmv[4 + j] += sigm(o1[j] + o3[j]) * cmO[4 + j];
        }
    }

    // ---- epilogue: hidden_sum -> hb[0][0] (hb[0] free since barrier of P=6)
    {
        f32x4 s0 = {hs[0], hs[1], hs[2], hs[3]};
        f32x4 s1 = {hs[4], hs[5], hs[6], hs[7]};
        *(bf16x8*)(&hb[0][0][0] + wb) = pack8(s0, s1);
    }
    asm volatile("s_waitcnt lgkmcnt(0)" ::: "memory");
    __builtin_amdgcn_s_barrier();
    __builtin_amdgcn_sched_barrier(0);

    bf16x8 afr[8];
    {
        const unsigned char* bc = &hb[0][0][0] + l15 * 512;
#pragma unroll
        for (int kk = 0; kk < 8; ++kk)
            afr[kk] = *(const bf16x8*)(bc + (((kk << 6) + (l4 << 4)) ^ swr));
    }

    // iou GEMM from packed Wiou (bf16, rows 256..1023 of wpk)
    float gq[3][8];
#pragma unroll
    for (int q = 0; q < 3; ++q) {
#pragma unroll
        for (int n = 0; n < 2; ++n) {
            const short* wr = wpk + (size_t)(256 + q * 256 + wc0 + n * 16 + l15) * DD + l4 * 8;
            f32x4 acc = {0.f, 0.f, 0.f, 0.f};
#pragma unroll
            for (int kk = 0; kk < 8; ++kk)
                acc = __builtin_amdgcn_mfma_f32_16x16x32_bf16(afr[kk], *(const bf16x8*)(wr + kk * 32), acc, 0, 0, 0);
            float bq = biou[q * 256 + wc0 + n * 16 + l15];
#pragma unroll
            for (int j = 0; j < 4; ++j) gq[q][n * 4 + j] = acc[j] + bq;
        }
    }

    // ---- gates + stores
    float* o0p = out + (size_t)(b0 + l4 * 4) * DD + wc0 + l15;
    float* o1p = o0p + SLAB;
#pragma unroll
    for (int n = 0; n < 2; ++n)
#pragma unroll
        for (int j = 0; j < 4; ++j) {
            float ig = sigm(gq[0][n * 4 + j]);
            float og = sigm(gq[1][n * 4 + j]);
            float ug = tanh_(gq[2][n * 4 + j]);
            float mm = nmv[n * 4 + j] + ig * ug;
            float hh = og * tanh_(mm);
            o0p[j * DD + n * 16] = mm;
            o1p[j * DD + n * 16] = hh;
        }
}

extern "C" void kernel_launch(void* const* d_in, const int* in_sizes, int n_in,
                              void* d_out, int out_size, void* d_ws, size_t ws_size,
                              hipStream_t stream) {
    const float* cmem = (const float*)d_in[0];
    const float* chid = (const float*)d_in[1];
    const float* Wf   = (const float*)d_in[2];
    const float* bf   = (const float*)d_in[3];
    const float* Wiou = (const float*)d_in[4];
    const float* biou = (const float*)d_in[5];
    float* out = (float*)d_out;
    short* wpk = (short*)d_ws;    // 1024 x 256 bf16 = 512 KiB

    prep<<<1024, 64, 0, stream>>>(Wf, Wiou, wpk);
    treelstm<<<BB / BT, NT, 0, stream>>>(cmem, chid, wpk, bf, biou, out);
}

// Round 6
// 165.095 us; speedup vs baseline: 2.6790x; 2.6790x over previous
//
#include <hip/hip_runtime.h>
#include <hip/hip_bf16.h>

#define CC 16
#define BB 16384
#define DD 256
#define BT 16
#define NT 512
#define SLAB ((size_t)BB * DD)

typedef float f32x4 __attribute__((ext_vector_type(4)));
typedef short bf16x8 __attribute__((ext_vector_type(8)));
typedef short bf16x4 __attribute__((ext_vector_type(4)));

static __device__ __forceinline__ short bfc(float f) {
    return (short)__builtin_bit_cast(unsigned short, __float2bfloat16(f));
}
static __device__ __forceinline__ bf16x8 pack8(f32x4 a, f32x4 b) {
    bf16x8 v;
    v[0] = bfc(a[0]); v[1] = bfc(a[1]); v[2] = bfc(a[2]); v[3] = bfc(a[3]);
    v[4] = bfc(b[0]); v[5] = bfc(b[1]); v[6] = bfc(b[2]); v[7] = bfc(b[3]);
    return v;
}
static __device__ __forceinline__ float sigm(float x) {
    return __builtin_amdgcn_rcpf(1.0f + __expf(-x));
}
static __device__ __forceinline__ float tanh_(float x) {
    return 2.0f * __builtin_amdgcn_rcpf(1.0f + __expf(-2.0f * x)) - 1.0f;
}

// ---- prep: pack Wf (rows 0..255) + Wiou (rows 256..1023) f32 -> bf16 row-major
__global__ void prep(const float* __restrict__ Wf, const float* __restrict__ Wiou,
                     short* __restrict__ ws) {
    const int row = blockIdx.x;          // 0..1023
    const int t   = threadIdx.x;         // 0..63
    const float* src = (row < 256) ? (Wf + (size_t)row * DD)
                                   : (Wiou + (size_t)(row - 256) * DD);
    f32x4 v = *(const f32x4*)(src + t * 4);
    bf16x4 o; o[0] = bfc(v[0]); o[1] = bfc(v[1]); o[2] = bfc(v[2]); o[3] = bfc(v[3]);
    *(bf16x4*)(ws + (size_t)row * DD + t * 4) = o;
}

// ---- main: TreeLSTM node update, pair-staged pipeline.
// 512 thr = 8 waves; BT=16 rows x 256 cols; wave owns 32 cols.
// LDS: 2 pair-buffers x 2 children x 8KB bf16 tiles, 4-bit XOR swizzle
// (chunk ^ row) -> conflict-free b128 read+write (R5: conflicts == 0).
// ONE barrier per 2 children (lgkmcnt-only drain; global loads cross it).
// launch_bounds (512,2): allocator lands in the 128-VGPR bucket (R1-proven),
// avoiding the 64-VGPR squeeze that spilled in R5 (WRITE 368MB, FETCH 1.15GB).
__global__ __launch_bounds__(NT, 2) void treelstm(
    const float* __restrict__ cmem,   // [C][B][D]
    const float* __restrict__ chid,   // [C][B][D]
    const short* __restrict__ wpk,    // packed bf16: Wf rows 0..255, Wiou 256..1023
    const float* __restrict__ bfv,    // [D]
    const float* __restrict__ biou,   // [3D]
    float* __restrict__ out)          // [2][B][D]
{
    __shared__ __align__(64) unsigned char hb[2][2][BT * DD * 2];   // 32 KiB

    const int tid  = threadIdx.x;
    const int lane = tid & 63;
    const int wid  = tid >> 6;     // 0..7
    const int l15  = lane & 15;
    const int l4   = lane >> 4;    // 0..3
    const int b0   = blockIdx.x * BT;
    const int wc0  = wid * 32;     // wave's 32 output columns
    const int swr  = l15 << 4;     // read-side 4-bit XOR (x16B)

    // staging: thread owns (row tid>>5, 16B-chunk tid&31)
    const int srow   = tid >> 5;
    const int schunk = tid & 31;
    const float* hg  = chid + (size_t)(b0 + srow) * DD + schunk * 8;
    const int wb     = srow * 512 + (((schunk ^ srow) & 31) << 4);

    // ---- issue h(0),h(1) first (weight setup hides latency)
    f32x4 hA0 = *(const f32x4*)(hg);
    f32x4 hA1 = *(const f32x4*)(hg + 4);
    f32x4 hA2 = *(const f32x4*)(hg + SLAB);
    f32x4 hA3 = *(const f32x4*)(hg + SLAB + 4);

    // Wf B-frags from packed bf16: 2 n-frags x 8 k = 32 VGPR
    bf16x8 wfr[2][8];
    float bfr[2];
#pragma unroll
    for (int n = 0; n < 2; ++n) {
        const short* wr = wpk + (size_t)(wc0 + n * 16 + l15) * DD + l4 * 8;
#pragma unroll
        for (int k = 0; k < 8; ++k) wfr[n][k] = *(const bf16x8*)(wr + k * 32);
        bfr[n] = bfv[wc0 + n * 16 + l15];
    }

    // cm base (C-frag layout: rows l4*4+j, col wc0+n*16+l15); cmE = cm(0)
    const float* cmp = cmem + (size_t)(b0 + l4 * 4) * DD + wc0 + l15;
    float cmE[8], cmO[8];
#pragma unroll
    for (int n = 0; n < 2; ++n)
#pragma unroll
        for (int j = 0; j < 4; ++j) cmE[n * 4 + j] = cmp[j * DD + n * 16];

    float hs[8], nmv[8];
#pragma unroll
    for (int i = 0; i < 8; ++i) { hs[i] = 0.f; nmv[i] = 0.f; }

    // ---- prologue: hs += pair0; write pair0 -> buffer 0; barrier
#pragma unroll
    for (int i = 0; i < 4; ++i) {
        hs[i] += hA0[i] + hA2[i];
        hs[4 + i] += hA1[i] + hA3[i];
    }
    *(bf16x8*)(&hb[0][0][0] + wb) = pack8(hA0, hA1);
    *(bf16x8*)(&hb[0][1][0] + wb) = pack8(hA2, hA3);
    asm volatile("s_waitcnt lgkmcnt(0)" ::: "memory");
    __builtin_amdgcn_s_barrier();
    __builtin_amdgcn_sched_barrier(0);

    const float* hgn = hg + 2 * SLAB;   // next-pair h source (children 2,3)
    const float* cmn = cmp + SLAB;      // next cm source (child 1)

#pragma unroll 1
    for (int P = 0; P < 8; ++P) {       // pair P = children {2P, 2P+1}
        // issue next pair's h (written to LDS at phase end)
        if (P < 7) {
            hA0 = *(const f32x4*)(hgn);
            hA1 = *(const f32x4*)(hgn + 4);
            hA2 = *(const f32x4*)(hgn + SLAB);
            hA3 = *(const f32x4*)(hgn + SLAB + 4);
            hgn += 2 * SLAB;
        }
        // issue cmO = cm(2P+1)
#pragma unroll
        for (int n = 0; n < 2; ++n)
#pragma unroll
            for (int j = 0; j < 4; ++j) cmO[n * 4 + j] = cmn[j * DD + n * 16];
        cmn += SLAB;

        // ---- child even: 8 ds_read_b128 + 16 MFMA (split accs, depth 4)
        f32x4 e0 = {bfr[0], bfr[0], bfr[0], bfr[0]};
        f32x4 e1 = {bfr[1], bfr[1], bfr[1], bfr[1]};
        f32x4 e2 = {0.f, 0.f, 0.f, 0.f}, e3 = {0.f, 0.f, 0.f, 0.f};
        const unsigned char* bcE = &hb[P & 1][0][0] + l15 * 512;
#pragma unroll
        for (int kk = 0; kk < 4; ++kk) {
            bf16x8 a = *(const bf16x8*)(bcE + ((((kk) << 6) + (l4 << 4)) ^ swr));
            e0 = __builtin_amdgcn_mfma_f32_16x16x32_bf16(a, wfr[0][kk], e0, 0, 0, 0);
            e1 = __builtin_amdgcn_mfma_f32_16x16x32_bf16(a, wfr[1][kk], e1, 0, 0, 0);
        }
#pragma unroll
        for (int kk = 4; kk < 8; ++kk) {
            bf16x8 a = *(const bf16x8*)(bcE + ((((kk) << 6) + (l4 << 4)) ^ swr));
            e2 = __builtin_amdgcn_mfma_f32_16x16x32_bf16(a, wfr[0][kk], e2, 0, 0, 0);
            e3 = __builtin_amdgcn_mfma_f32_16x16x32_bf16(a, wfr[1][kk], e3, 0, 0, 0);
        }
        // even nmv (fills odd child's ds_read shadow)
#pragma unroll
        for (int j = 0; j < 4; ++j) {
            nmv[j]     += sigm(e0[j] + e2[j]) * cmE[j];
            nmv[4 + j] += sigm(e1[j] + e3[j]) * cmE[4 + j];
        }
        // refill cmE = cm(2P+2)
        if (P < 7) {
#pragma unroll
            for (int n = 0; n < 2; ++n)
#pragma unroll
                for (int j = 0; j < 4; ++j) cmE[n * 4 + j] = cmn[j * DD + n * 16];
        }
        cmn += SLAB;

        // ---- child odd
        f32x4 o0 = {bfr[0], bfr[0], bfr[0], bfr[0]};
        f32x4 o1 = {bfr[1], bfr[1], bfr[1], bfr[1]};
        f32x4 o2 = {0.f, 0.f, 0.f, 0.f}, o3 = {0.f, 0.f, 0.f, 0.f};
        const unsigned char* bcO = &hb[P & 1][1][0] + l15 * 512;
#pragma unroll
        for (int kk = 0; kk < 4; ++kk) {
            bf16x8 a = *(const bf16x8*)(bcO + ((((kk) << 6) + (l4 << 4)) ^ swr));
            o0 = __builtin_amdgcn_mfma_f32_16x16x32_bf16(a, wfr[0][kk], o0, 0, 0, 0);
            o1 = __builtin_amdgcn_mfma_f32_16x16x32_bf16(a, wfr[1][kk], o1, 0, 0, 0);
        }
#pragma unroll
        for (int kk = 4; kk < 8; ++kk) {
            bf16x8 a = *(const bf16x8*)(bcO + ((((kk) << 6) + (l4 << 4)) ^ swr));
            o2 = __builtin_amdgcn_mfma_f32_16x16x32_bf16(a, wfr[0][kk], o2, 0, 0, 0);
            o3 = __builtin_amdgcn_mfma_f32_16x16x32_bf16(a, wfr[1][kk], o3, 0, 0, 0);
        }

        // ---- hs += next pair; write it; ONE barrier per pair
        if (P < 7) {
#pragma unroll
            for (int i = 0; i < 4; ++i) {
                hs[i] += hA0[i] + hA2[i];
                hs[4 + i] += hA1[i] + hA3[i];
            }
            *(bf16x8*)(&hb[(P & 1) ^ 1][0][0] + wb) = pack8(hA0, hA1);
            *(bf16x8*)(&hb[(P & 1) ^ 1][1][0] + wb) = pack8(hA2, hA3);
            asm volatile("s_waitcnt lgkmcnt(0)" ::: "memory");
            __builtin_amdgcn_s_barrier();
            __builtin_amdgcn_sched_barrier(0);
        }

        // odd nmv (post-barrier: fills next phase's ds_read window)
#pragma unroll
        for (int j = 0; j < 4; ++j) {
            nmv[j]     += sigm(o0[j] + o2[j]) * cmO[j];
            nmv[4 + j] += sigm(o1[j] + o3[j]) * cmO[4 + j];
        }
    }

    // ---- epilogue: hidden_sum -> hb[0][0] (hb[0] free since barrier of P=6)
    {
        f32x4 s0 = {hs[0], hs[1], hs[2], hs[3]};
        f32x4 s1 = {hs[4], hs[5], hs[6], hs[7]};
        *(bf16x8*)(&hb[0][0][0] + wb) = pack8(s0, s1);
    }
    asm volatile("s_waitcnt lgkmcnt(0)" ::: "memory");
    __builtin_amdgcn_s_barrier();
    __builtin_amdgcn_sched_barrier(0);

    bf16x8 afr[8];
    {
        const unsigned char* bc = &hb[0][0][0] + l15 * 512;
#pragma unroll
        for (int kk = 0; kk < 8; ++kk)
            afr[kk] = *(const bf16x8*)(bc + (((kk << 6) + (l4 << 4)) ^ swr));
    }

    // iou GEMM from packed Wiou (bf16, rows 256..1023 of wpk)
    float gq[3][8];
#pragma unroll
    for (int q = 0; q < 3; ++q) {
#pragma unroll
        for (int n = 0; n < 2; ++n) {
            const short* wr = wpk + (size_t)(256 + q * 256 + wc0 + n * 16 + l15) * DD + l4 * 8;
            f32x4 acc = {0.f, 0.f, 0.f, 0.f};
#pragma unroll
            for (int kk = 0; kk < 8; ++kk)
                acc = __builtin_amdgcn_mfma_f32_16x16x32_bf16(afr[kk], *(const bf16x8*)(wr + kk * 32), acc, 0, 0, 0);
            float bq = biou[q * 256 + wc0 + n * 16 + l15];
#pragma unroll
            for (int j = 0; j < 4; ++j) gq[q][n * 4 + j] = acc[j] + bq;
        }
    }

    // ---- gates + stores
    float* o0p = out + (size_t)(b0 + l4 * 4) * DD + wc0 + l15;
    float* o1p = o0p + SLAB;
#pragma unroll
    for (int n = 0; n < 2; ++n)
#pragma unroll
        for (int j = 0; j < 4; ++j) {
            float ig = sigm(gq[0][n * 4 + j]);
            float og = sigm(gq[1][n * 4 + j]);
            float ug = tanh_(gq[2][n * 4 + j]);
            float mm = nmv[n * 4 + j] + ig * ug;
            float hh = og * tanh_(mm);
            o0p[j * DD + n * 16] = mm;
            o1p[j * DD + n * 16] = hh;
        }
}

extern "C" void kernel_launch(void* const* d_in, const int* in_sizes, int n_in,
                              void* d_out, int out_size, void* d_ws, size_t ws_size,
                              hipStream_t stream) {
    const float* cmem = (const float*)d_in[0];
    const float* chid = (const float*)d_in[1];
    const float* Wf   = (const float*)d_in[2];
    const float* bf   = (const float*)d_in[3];
    const float* Wiou = (const float*)d_in[4];
    const float* biou = (const float*)d_in[5];
    float* out = (float*)d_out;
    short* wpk = (short*)d_ws;    // 1024 x 256 bf16 = 512 KiB

    prep<<<1024, 64, 0, stream>>>(Wf, Wiou, wpk);
    treelstm<<<BB / BT, NT, 0, stream>>>(cmem, chid, wpk, bf, biou, out);
}